// Round 3
// baseline (826.870 us; speedup 1.0000x reference)
//
#include <hip/hip_runtime.h>

// ---------------------------------------------------------------------------
// Conformer block, MI355X gfx950. Inputs/outputs fp32; internal activations
// bf16 (raw short bit-handling) with fp32 accumulation via bf16 MFMA 16x16x32.
// ---------------------------------------------------------------------------

typedef __attribute__((ext_vector_type(4))) float f32x4;
typedef __attribute__((ext_vector_type(8))) short short8;
typedef __attribute__((ext_vector_type(4))) short s16x4;

__device__ __forceinline__ float bfs2f(short s) {
  unsigned u = ((unsigned)(unsigned short)s) << 16;
  float f; __builtin_memcpy(&f, &u, 4); return f;
}
__device__ __forceinline__ short f2bfs(float f) {
  unsigned u; __builtin_memcpy(&u, &f, 4);
  u = (u + 0x7FFFu + ((u >> 16) & 1u)) >> 16;   // RNE
  return (short)u;
}
__device__ __forceinline__ float sigmoidf_(float x) { return 1.f / (1.f + __expf(-x)); }

#define GLOADLDS(gsrc, ldst) \
  __builtin_amdgcn_global_load_lds((__attribute__((address_space(1))) void*)(gsrc), \
                                   (__attribute__((address_space(3))) void*)(ldst), 16, 0, 0)

enum { EPI_SILU = 0, EPI_F32BIAS = 1, EPI_RES = 2, EPI_QKV = 3, EPI_SPLAIN = 4, EPI_SCRAM = 5 };

// ---------------------------------------------------------------------------
// Generic GEMM: C[M,N] = A[M,K] * BT[N,K]^T, bf16 in, fp32 accum.
// m97 structure: global_load_lds(16B) staging, ds_read_b128 frags, 2-barrier.
// Batched via blockIdx.z with split z-strides (A/B in elements, C in bytes).
// ---------------------------------------------------------------------------
template<int BM, int BN, int WM, int WN, int EPI>
__global__ __launch_bounds__(256) void gemm_bt(
    const short* __restrict__ A, int lda, long zAh, long zAl,
    const short* __restrict__ BT, int ldbt, long zBh, long zBl,
    int K,
    void* C, int ldc, long zCh, long zCl, int zdiv,
    const float* bias, const float* bias2, const float* bias3,
    const float* resid, float alpha, float beta)
{
  constexpr int FM = BM / (WM * 16), FN = BN / (WN * 16);
  constexpr int AIT = (BM * 4) / 256, BIT = (BN * 4) / 256;
  __shared__ short sA[BM * 32];
  __shared__ short sB[BN * 32];
  const int tid = threadIdx.x;
  const int zhi = (int)(blockIdx.z >> zdiv);
  const int zlo = (int)(blockIdx.z & ((1u << zdiv) - 1u));
  A  += (long)zhi * zAh + (long)zlo * zAl;
  BT += (long)zhi * zBh + (long)zlo * zBl;
  char* cbase = (char*)C + (long)zhi * zCh + (long)zlo * zCl;
  const int m0 = blockIdx.x * BM, n0 = blockIdx.y * BN;

  f32x4 acc[FM][FN];
#pragma unroll
  for (int i = 0; i < FM; ++i) {
#pragma unroll
    for (int j = 0; j < FN; ++j) acc[i][j] = (f32x4){0.f, 0.f, 0.f, 0.f};
  }
  const int lane = tid & 63, wid = tid >> 6;
  const int wm = wid / WN, wn = wid % WN;
  const int lr = lane & 15, kg = lane >> 4;
  const int aRow = wm * (BM / WM), bRow = wn * (BN / WN);

  for (int k0 = 0; k0 < K; k0 += 32) {
    __syncthreads();
#pragma unroll
    for (int it = 0; it < AIT; ++it) {
      int idx = it * 256 + tid;
      const short* src = A + (long)(m0 + (idx >> 2)) * lda + k0 + (idx & 3) * 8;
      GLOADLDS(src, &sA[idx * 8]);
    }
#pragma unroll
    for (int it = 0; it < BIT; ++it) {
      int idx = it * 256 + tid;
      const short* src = BT + (long)(n0 + (idx >> 2)) * ldbt + k0 + (idx & 3) * 8;
      GLOADLDS(src, &sB[idx * 8]);
    }
    asm volatile("s_waitcnt vmcnt(0)" ::: "memory");
    __syncthreads();
    short8 af[FM], bfr[FN];
#pragma unroll
    for (int mi = 0; mi < FM; ++mi)
      af[mi] = *(const short8*)&sA[(aRow + mi * 16 + lr) * 32 + kg * 8];
#pragma unroll
    for (int ni = 0; ni < FN; ++ni)
      bfr[ni] = *(const short8*)&sB[(bRow + ni * 16 + lr) * 32 + kg * 8];
#pragma unroll
    for (int mi = 0; mi < FM; ++mi) {
#pragma unroll
      for (int ni = 0; ni < FN; ++ni)
        acc[mi][ni] = __builtin_amdgcn_mfma_f32_16x16x32_bf16(af[mi], bfr[ni], acc[mi][ni], 0, 0, 0);
    }
  }

  // epilogue: C/D layout col = lane&15, row = (lane>>4)*4 + reg
  const int baseRow = m0 + aRow, baseCol = n0 + bRow;
#pragma unroll
  for (int mi = 0; mi < FM; ++mi) {
#pragma unroll
    for (int ni = 0; ni < FN; ++ni) {
      const int col = baseCol + ni * 16 + lr;
#pragma unroll
      for (int r = 0; r < 4; ++r) {
        const int row = baseRow + mi * 16 + kg * 4 + r;
        float v = acc[mi][ni][r];
        if (EPI == EPI_SILU) {
          v += bias[col];
          v = v * sigmoidf_(v);
          ((short*)cbase)[(long)row * ldc + col] = f2bfs(v);
        } else if (EPI == EPI_F32BIAS) {
          v += bias[col];
          ((float*)cbase)[(long)row * ldc + col] = v;
        } else if (EPI == EPI_RES) {
          v += bias[col];
          float rv = resid[(long)row * ldc + col];
          ((float*)cbase)[(long)row * ldc + col] = alpha * rv + beta * v;
        } else if (EPI == EPI_QKV) {
          if (col < 512)       v = (v + bias[col]) * 0.125f;   // fold 1/sqrt(64) into q
          else if (col < 1024) v += bias2[col - 512];
          else                 v += bias3[col - 1024];
          ((short*)cbase)[(long)row * ldc + col] = f2bfs(v);
        } else if (EPI == EPI_SPLAIN) {
          ((float*)cbase)[(long)row * ldc + col] = v;
        } else if (EPI == EPI_SCRAM) {
          // o[b,h,t2,e] -> out[b, n>>3, (n&7)*64+e], n = h*1024 + t2 (h = zlo)
          int n = zlo * 1024 + row;
          ((short*)cbase)[(long)(n >> 3) * 512 + (n & 7) * 64 + col] = f2bfs(v);
        }
      }
    }
  }
}

// ---------------------------------------------------------------------------
// Conv as implicit GEMM. K-dim = (kk, i) with 31*16 = 496 K-steps of 32.
// A rows come from zero-halo-padded glu buffer [8][1056][512] (data at +16).
// BT = wdKT[kk][e][i]. Epilogue: z bf16 + per-channel sum/sumsq for BatchNorm.
// ---------------------------------------------------------------------------
__global__ __launch_bounds__(256) void conv_gemm(
    const short* __restrict__ glu_pad, const short* __restrict__ wdKT,
    short* __restrict__ zout, float* stats)
{
  __shared__ short sA[64 * 32];
  __shared__ short sB[128 * 32];
  __shared__ float lsum[128], lsq[128];
  const int tid = threadIdx.x;
  const int b = blockIdx.z;
  const int t0 = blockIdx.x * 64, n0 = blockIdx.y * 128;
  const short* gbase = glu_pad + (long)b * 1056 * 512;

  f32x4 acc[2][4];
#pragma unroll
  for (int i = 0; i < 2; ++i) {
#pragma unroll
    for (int j = 0; j < 4; ++j) acc[i][j] = (f32x4){0.f, 0.f, 0.f, 0.f};
  }
  const int lane = tid & 63, wid = tid >> 6;
  const int wm = wid >> 1, wn = wid & 1;
  const int lr = lane & 15, kg = lane >> 4;
  const int aRow = wm * 32, bRow = wn * 64;

  for (int kk = 0; kk < 31; ++kk) {
    const short* abase = gbase + (long)(t0 + 1 + kk) * 512;  // 16 + t0 + kk - 15
    for (int ib = 0; ib < 16; ++ib) {
      __syncthreads();
      {
        int idx = tid;  // 64 rows * 4 chunks = 256
        const short* src = abase + (long)(idx >> 2) * 512 + ib * 32 + (idx & 3) * 8;
        GLOADLDS(src, &sA[idx * 8]);
      }
#pragma unroll
      for (int it = 0; it < 2; ++it) {
        int idx = it * 256 + tid;
        const short* src = wdKT + ((long)kk * 512 + n0 + (idx >> 2)) * 512 + ib * 32 + (idx & 3) * 8;
        GLOADLDS(src, &sB[idx * 8]);
      }
      asm volatile("s_waitcnt vmcnt(0)" ::: "memory");
      __syncthreads();
      short8 af[2], bfr[4];
#pragma unroll
      for (int mi = 0; mi < 2; ++mi)
        af[mi] = *(const short8*)&sA[(aRow + mi * 16 + lr) * 32 + kg * 8];
#pragma unroll
      for (int ni = 0; ni < 4; ++ni)
        bfr[ni] = *(const short8*)&sB[(bRow + ni * 16 + lr) * 32 + kg * 8];
#pragma unroll
      for (int mi = 0; mi < 2; ++mi) {
#pragma unroll
        for (int ni = 0; ni < 4; ++ni)
          acc[mi][ni] = __builtin_amdgcn_mfma_f32_16x16x32_bf16(af[mi], bfr[ni], acc[mi][ni], 0, 0, 0);
      }
    }
  }

  if (tid < 128) { lsum[tid] = 0.f; lsq[tid] = 0.f; }
  __syncthreads();
#pragma unroll
  for (int ni = 0; ni < 4; ++ni) {
    const int cloc = bRow + ni * 16 + lr;
    const int col = n0 + cloc;
    float s = 0.f, q = 0.f;
#pragma unroll
    for (int mi = 0; mi < 2; ++mi) {
#pragma unroll
      for (int r = 0; r < 4; ++r) {
        const int row = t0 + aRow + mi * 16 + kg * 4 + r;
        float v = acc[mi][ni][r];
        zout[((long)b * 1024 + row) * 512 + col] = f2bfs(v);
        s += v; q += v * v;
      }
    }
    atomicAdd(&lsum[cloc], s);
    atomicAdd(&lsq[cloc], q);
  }
  __syncthreads();
  if (tid < 128) {
    atomicAdd(&stats[n0 + tid], lsum[tid]);
    atomicAdd(&stats[512 + n0 + tid], lsq[tid]);
  }
}

// ---------------------------------------------------------------------------
// LayerNorm rows of 512 (fp32 in), one wave per row (4 rows/block).
// Output bf16 (internal) or fp32 (final). Optional +PE after affine.
// ---------------------------------------------------------------------------
template<int ADDPE, int OUTF32>
__global__ __launch_bounds__(256) void ln_rows(
    const float* __restrict__ X, const float* __restrict__ g, const float* __restrict__ b,
    const float* __restrict__ pe, void* __restrict__ Y)
{
  const int row = blockIdx.x * 4 + (threadIdx.x >> 6);
  const int lane = threadIdx.x & 63;
  const int c0 = lane * 8;
  const float* src = X + (long)row * 512 + c0;
  f32x4 a = *(const f32x4*)src, c = *(const f32x4*)(src + 4);
  float x[8] = {a[0], a[1], a[2], a[3], c[0], c[1], c[2], c[3]};
  float s = 0.f, q = 0.f;
#pragma unroll
  for (int j = 0; j < 8; ++j) { s += x[j]; q += x[j] * x[j]; }
#pragma unroll
  for (int off = 32; off > 0; off >>= 1) { s += __shfl_xor(s, off); q += __shfl_xor(q, off); }
  const float mean = s * (1.f / 512.f);
  const float var = q * (1.f / 512.f) - mean * mean;
  const float rstd = rsqrtf(var + 1e-5f);
  f32x4 g0 = *(const f32x4*)(g + c0), g1 = *(const f32x4*)(g + c0 + 4);
  f32x4 b0 = *(const f32x4*)(b + c0), b1 = *(const f32x4*)(b + c0 + 4);
  float gg[8] = {g0[0], g0[1], g0[2], g0[3], g1[0], g1[1], g1[2], g1[3]};
  float bb[8] = {b0[0], b0[1], b0[2], b0[3], b1[0], b1[1], b1[2], b1[3]};
  float y[8];
#pragma unroll
  for (int j = 0; j < 8; ++j) {
    y[j] = (x[j] - mean) * rstd * gg[j] + bb[j];
    if (ADDPE) y[j] += pe[(long)(row & 1023) * 512 + c0 + j];
  }
  if (OUTF32) {
    float* dst = (float*)Y + (long)row * 512 + c0;
    *(f32x4*)dst = (f32x4){y[0], y[1], y[2], y[3]};
    *(f32x4*)(dst + 4) = (f32x4){y[4], y[5], y[6], y[7]};
  } else {
    short8 o;
#pragma unroll
    for (int j = 0; j < 8; ++j) o[j] = f2bfs(y[j]);
    *(short8*)((short*)Y + (long)row * 512 + c0) = o;
  }
}

// ---------------------------------------------------------------------------
// Row softmax over 1024 fp32 -> bf16. One wave per row.
// ---------------------------------------------------------------------------
__global__ __launch_bounds__(256) void softmax_rows(const float* __restrict__ S, short* __restrict__ P)
{
  const int gw = blockIdx.x * 4 + (threadIdx.x >> 6);
  const int lane = threadIdx.x & 63;
  const float* row = S + (long)gw * 1024;
  f32x4 v[4];
  float m = -3.4e38f;
#pragma unroll
  for (int i = 0; i < 4; ++i) {
    v[i] = ((const f32x4*)row)[i * 64 + lane];
#pragma unroll
    for (int j = 0; j < 4; ++j) m = fmaxf(m, v[i][j]);
  }
#pragma unroll
  for (int off = 32; off > 0; off >>= 1) m = fmaxf(m, __shfl_xor(m, off));
  float s = 0.f;
#pragma unroll
  for (int i = 0; i < 4; ++i) {
#pragma unroll
    for (int j = 0; j < 4; ++j) { v[i][j] = __expf(v[i][j] - m); s += v[i][j]; }
  }
#pragma unroll
  for (int off = 32; off > 0; off >>= 1) s += __shfl_xor(s, off);
  const float inv = 1.f / s;
  short* prow = P + (long)gw * 1024;
#pragma unroll
  for (int i = 0; i < 4; ++i) {
    s16x4 o;
#pragma unroll
    for (int j = 0; j < 4; ++j) o[j] = f2bfs(v[i][j] * inv);
    ((s16x4*)prow)[i * 64 + lane] = o;
  }
}

// ---------------------------------------------------------------------------
// 64x64-tile transpose -> bf16 out. INF32: fp32 input (weights) or bf16 input.
// out[c][r] = in[r][c]. Batched via blockIdx.z with split strides.
// ---------------------------------------------------------------------------
template<int INF32>
__global__ __launch_bounds__(256) void transpose64(
    const void* __restrict__ in_, int ldin, short* __restrict__ out, int ldout,
    int ctiles, int zshift, long zh_in, long zl_in, long z_out)
{
  __shared__ short t[64][72];
  const int z = blockIdx.z;
  const long inoff = (long)(z >> zshift) * zh_in + (long)(z & ((1 << zshift) - 1)) * zl_in;
  const int tr = blockIdx.x / ctiles, tc = blockIdx.x % ctiles;
  short* dst = out + (long)z * z_out + (long)(tc * 64) * ldout + tr * 64;
  const int tid = threadIdx.x;
#pragma unroll
  for (int p = 0; p < 2; ++p) {
    int idx = p * 256 + tid;
    int r = idx >> 3, c8 = (idx & 7) * 8;
    if (INF32) {
      const float* src = (const float*)in_ + inoff + (long)(tr * 64 + r) * ldin + tc * 64 + c8;
      f32x4 v0 = *(const f32x4*)src, v1 = *(const f32x4*)(src + 4);
#pragma unroll
      for (int j = 0; j < 4; ++j) { t[r][c8 + j] = f2bfs(v0[j]); t[r][c8 + 4 + j] = f2bfs(v1[j]); }
    } else {
      const short* src = (const short*)in_ + inoff + (long)(tr * 64 + r) * ldin + tc * 64 + c8;
      short8 v = *(const short8*)src;
#pragma unroll
      for (int j = 0; j < 8; ++j) t[r][c8 + j] = v[j];
    }
  }
  __syncthreads();
#pragma unroll
  for (int p = 0; p < 2; ++p) {
    int idx = p * 256 + tid;
    int c = idx >> 3, r8 = (idx & 7) * 8;
    short8 v;
#pragma unroll
    for (int j = 0; j < 8; ++j) v[j] = t[r8 + j][c];
    *(short8*)(dst + (long)c * ldout + r8) = v;
  }
}

// wdKT[kk][e][i] = wd[e][i][kk], fp32 -> bf16
__global__ __launch_bounds__(256) void wd_pack(const float* __restrict__ wd, short* __restrict__ wdKT)
{
  const int gid = blockIdx.x * 256 + threadIdx.x;  // 262144 = 512*512
  const int e = gid >> 9, i = gid & 511;
  const float* src = wd + ((long)e * 512 + i) * 31;
#pragma unroll
  for (int kk = 0; kk < 31; ++kk)
    wdKT[((long)kk * 512 + e) * 512 + i] = f2bfs(src[kk]);
}

// pe[t][2p] = sin(t * 10000^(-p/256)), pe[t][2p+1] = cos(...)
__global__ __launch_bounds__(256) void pe_init(float* __restrict__ pe)
{
  const int gid = blockIdx.x * 256 + threadIdx.x;  // 262144 = 1024*256
  const int t = gid >> 8, p = gid & 255;
  const float freq = __expf(-(float)p * (9.210340371976184f / 256.f));
  const float ang = (float)t * freq;
  pe[(long)t * 512 + 2 * p]     = sinf(ang);
  pe[(long)t * 512 + 2 * p + 1] = cosf(ang);
}

// glu = a * sigmoid(g) from y1[N][1024] fp32 -> glu_pad[b][16+t][512] bf16
__global__ __launch_bounds__(256) void glu_kernel(const float* __restrict__ y1, short* __restrict__ gp)
{
  const int gid = blockIdx.x * 256 + threadIdx.x;  // 1048576
  const int row = gid >> 7;
  const int ci = (gid & 127) * 4;
  const float* base = y1 + (long)row * 1024;
  f32x4 a = *(const f32x4*)(base + ci);
  f32x4 g = *(const f32x4*)(base + 512 + ci);
  const int b = row >> 10, t = row & 1023;
  s16x4 o;
#pragma unroll
  for (int j = 0; j < 4; ++j) o[j] = f2bfs(a[j] * sigmoidf_(g[j]));
  *(s16x4*)(gp + ((long)b * 1056 + 16 + t) * 512 + ci) = o;
}

__global__ void bn_stats(float* stats, const float* __restrict__ bn_g, const float* __restrict__ bn_b)
{
  const int c = blockIdx.x * 256 + threadIdx.x;
  if (c < 512) {
    float mean = stats[c] * (1.f / 8192.f);
    float var = stats[512 + c] * (1.f / 8192.f) - mean * mean;
    float sc = bn_g[c] * rsqrtf(var + 1e-5f);
    stats[1024 + c] = sc;
    stats[1536 + c] = bn_b[c] - mean * sc;
  }
}

__global__ __launch_bounds__(256) void bn_silu(const short* __restrict__ z, const float* __restrict__ stats,
                                               short* __restrict__ out)
{
  const long base = ((long)blockIdx.x * 256 + threadIdx.x) * 8;
  const int c0 = (int)(base & 511);
  short8 v = *(const short8*)(z + base);
  short8 o;
#pragma unroll
  for (int j = 0; j < 8; ++j) {
    const int c = c0 + j;
    float y = bfs2f(v[j]) * stats[1024 + c] + stats[1536 + c];
    o[j] = f2bfs(y * sigmoidf_(y));
  }
  *(short8*)(out + base) = o;
}

// ---------------------------------------------------------------------------
extern "C" void kernel_launch(void* const* d_in, const int* in_sizes, int n_in,
                              void* d_out, int out_size, void* d_ws, size_t ws_size,
                              hipStream_t stream)
{
  (void)in_sizes; (void)n_in; (void)out_size; (void)ws_size;
  const float* x_in   = (const float*)d_in[0];
  const float* ff1_g  = (const float*)d_in[1];
  const float* ff1_bb = (const float*)d_in[2];
  const float* ff1_w1 = (const float*)d_in[3];
  const float* ff1_b1 = (const float*)d_in[4];
  const float* ff1_w2 = (const float*)d_in[5];
  const float* ff1_b2 = (const float*)d_in[6];
  const float* mha_g  = (const float*)d_in[7];
  const float* mha_b  = (const float*)d_in[8];
  const float* wq     = (const float*)d_in[9];
  const float* bq     = (const float*)d_in[10];
  const float* wk     = (const float*)d_in[11];
  const float* bk     = (const float*)d_in[12];
  const float* wv     = (const float*)d_in[13];
  const float* bv     = (const float*)d_in[14];
  const float* wo     = (const float*)d_in[15];
  const float* bo     = (const float*)d_in[16];
  const float* cv_g   = (const float*)d_in[17];
  const float* cv_b   = (const float*)d_in[18];
  const float* cv_w1  = (const float*)d_in[19];
  const float* cv_b1  = (const float*)d_in[20];
  const float* cv_wd  = (const float*)d_in[21];
  const float* bn_g   = (const float*)d_in[22];
  const float* bn_b   = (const float*)d_in[23];
  const float* cv_w2  = (const float*)d_in[24];
  const float* cv_b2  = (const float*)d_in[25];
  const float* ff2_g  = (const float*)d_in[26];
  const float* ff2_b  = (const float*)d_in[27];
  const float* ff2_w1 = (const float*)d_in[28];
  const float* ff2_b1 = (const float*)d_in[29];
  const float* ff2_w2 = (const float*)d_in[30];
  const float* ff2_b2 = (const float*)d_in[31];
  const float* fin_g  = (const float*)d_in[32];
  const float* fin_b  = (const float*)d_in[33];

  size_t off = 0;
  char* wsb = (char*)d_ws;
  auto take = [&](size_t n) { char* p = wsb + off; off += (n + 255) & ~(size_t)255; return p; };
  short* ff1w1T = (short*)take(2048L * 512 * 2);
  short* ff1w2T = (short*)take(512L * 2048 * 2);
  short* qkvT   = (short*)take(1536L * 512 * 2);
  short* woT    = (short*)take(512L * 512 * 2);
  short* cw1b   = (short*)take(1024L * 512 * 2);   // cv_w1 bf16 (already [out,in])
  short* cw2b   = (short*)take(512L * 512 * 2);    // cv_w2 bf16
  short* wdKT   = (short*)take(31L * 512 * 512 * 2);
  short* ff2w1T = (short*)take(2048L * 512 * 2);
  short* ff2w2T = (short*)take(512L * 2048 * 2);
  float* xcur   = (float*)take(8192L * 512 * 4);
  char*  Ra     = take(8192L * 2048 * 4);          // hid bf16 / qkv bf16 / y1 fp32
  short* Rb     = (short*)take(8192L * 512 * 2);   // ln out / att_o / conv z
  short* Rg     = (short*)take(8L * 1056 * 512 * 2); // glu_pad / bn act
  float* Rs     = (float*)take(16L * 1024 * 1024 * 4); // scores chunk (2 batches)
  short* Rp     = (short*)take(16L * 1024 * 1024 * 2); // probs chunk
  short* vt     = (short*)take(64L * 64 * 1024 * 2);   // V^T per (b,h)
  float* pe     = (float*)take(1024L * 512 * 4);
  float* stats  = (float*)take(2048L * 4);

  short* hid = (short*)Ra;
  short* qkv = (short*)Ra;
  float* y1  = (float*)Ra;

  // ---- weight packs (fp32 -> bf16; per call) ----
  transpose64<1><<<dim3(256, 1, 1), 256, 0, stream>>>(ff1_w1, 2048, ff1w1T, 512, 32, 0, 0, 0, 0);
  transpose64<1><<<dim3(256, 1, 1), 256, 0, stream>>>(ff1_w2, 512, ff1w2T, 2048, 8, 0, 0, 0, 0);
  transpose64<1><<<dim3(8, 1, 8), 256, 0, stream>>>(wq, 64, qkvT, 512, 1, 0, 32768, 0, 32768);
  transpose64<1><<<dim3(8, 1, 8), 256, 0, stream>>>(wk, 64, qkvT + 512 * 512, 512, 1, 0, 32768, 0, 32768);
  transpose64<1><<<dim3(8, 1, 8), 256, 0, stream>>>(wv, 64, qkvT + 1024 * 512, 512, 1, 0, 32768, 0, 32768);
  transpose64<1><<<dim3(64, 1, 1), 256, 0, stream>>>(wo, 512, woT, 512, 8, 0, 0, 0, 0);
  transpose64<1><<<dim3(256, 1, 1), 256, 0, stream>>>(ff2_w1, 2048, ff2w1T, 512, 32, 0, 0, 0, 0);
  transpose64<1><<<dim3(256, 1, 1), 256, 0, stream>>>(ff2_w2, 512, ff2w2T, 2048, 8, 0, 0, 0, 0);
  // cv_w1 [1024][512], cv_w2 [512][512] are already [out,in]: transpose twice = pack via two T's
  // simpler: wd_pack-style direct bf16 casts using transpose64 on the transposed view is wrong;
  // use a plain cast: reuse glu-style elementwise kernel via transpose64<1> with identity is not
  // available, so do it with a tiny dedicated pass: (grid covers all elements)
  {
    // pack cv_w1/cv_w2 to bf16 row-major [out][in] without transpose
    // (cheap elementwise: 0.75M elements)
    auto dummy = 0; (void)dummy;
  }
  wd_pack<<<1024, 256, 0, stream>>>(cv_wd, wdKT);
  pe_init<<<1024, 256, 0, stream>>>(pe);
  // elementwise bf16 casts for cv_w1 (524288) and cv_w2 (262144)
  {
    struct Cast { };
  }
  // use glu-independent cast kernels launched below via lambda-less dedicated kernel:
  extern __global__ void cast_bf16(const float*, short*, long);
  cast_bf16<<<2048, 256, 0, stream>>>(cv_w1, cw1b, 524288L);
  cast_bf16<<<1024, 256, 0, stream>>>(cv_w2, cw2b, 262144L);

  // ---- FF1: x1 = 1.5 x + 0.5 (silu(ln(x) W1 + b1) W2 + b2) ----
  ln_rows<0, 0><<<2048, 256, 0, stream>>>(x_in, ff1_g, ff1_bb, nullptr, Rb);
  gemm_bt<128, 128, 2, 2, EPI_SILU><<<dim3(64, 16, 1), 256, 0, stream>>>(
      Rb, 512, 0, 0, ff1w1T, 512, 0, 0, 512,
      hid, 2048, 0, 0, 0, ff1_b1, nullptr, nullptr, nullptr, 0.f, 0.f);
  gemm_bt<128, 128, 2, 2, EPI_RES><<<dim3(64, 4, 1), 256, 0, stream>>>(
      hid, 2048, 0, 0, ff1w2T, 2048, 0, 0, 2048,
      xcur, 512, 0, 0, 0, ff1_b2, nullptr, nullptr, x_in, 1.5f, 0.5f);

  // ---- MHSA: x2 = 2 x1 + (scramble(attn) Wo + bo) ----
  ln_rows<1, 0><<<2048, 256, 0, stream>>>(xcur, mha_g, mha_b, pe, Rb);
  gemm_bt<128, 128, 2, 2, EPI_QKV><<<dim3(64, 12, 1), 256, 0, stream>>>(
      Rb, 512, 0, 0, qkvT, 512, 0, 0, 512,
      qkv, 1536, 0, 0, 0, bq, bk, bv, nullptr, 0.f, 0.f);
  transpose64<0><<<dim3(16, 1, 64), 256, 0, stream>>>(qkv + 1024, 1536, vt, 1024, 1, 3,
                                                      1024L * 1536, 64, 65536);
  for (int b0 = 0; b0 < 8; b0 += 2) {
    const short* qb = qkv + (long)b0 * 1024 * 1536;
    gemm_bt<128, 128, 2, 2, EPI_SPLAIN><<<dim3(8, 8, 16), 256, 0, stream>>>(
        qb, 1536, 1024L * 1536, 64,
        qb + 512, 1536, 1024L * 1536, 64,
        64,
        Rs, 1024, 33554432L, 4194304L, 3,
        nullptr, nullptr, nullptr, nullptr, 0.f, 0.f);
    softmax_rows<<<4096, 256, 0, stream>>>(Rs, Rp);
    gemm_bt<128, 64, 4, 1, EPI_SCRAM><<<dim3(8, 1, 16), 256, 0, stream>>>(
        Rp, 1024, 8L * 1048576, 1048576L,
        vt + (long)b0 * 8 * 65536, 1024, 8L * 65536, 65536L,
        1024,
        Rb + (long)b0 * 1024 * 512, 512, 1048576L, 0L, 3,
        nullptr, nullptr, nullptr, nullptr, 0.f, 0.f);
  }
  gemm_bt<128, 128, 2, 2, EPI_RES><<<dim3(64, 4, 1), 256, 0, stream>>>(
      Rb, 512, 0, 0, woT, 512, 0, 0, 512,
      xcur, 512, 0, 0, 0, bo, nullptr, nullptr, xcur, 2.f, 1.f);

  // ---- Conv module: x3 = 2 x2 + (W2 silu(BN(conv(glu(W1 ln(x2) + b1)))) + b2) ----
  ln_rows<0, 0><<<2048, 256, 0, stream>>>(xcur, cv_g, cv_b, nullptr, Rb);
  gemm_bt<128, 128, 2, 2, EPI_F32BIAS><<<dim3(64, 8, 1), 256, 0, stream>>>(
      Rb, 512, 0, 0, cw1b, 512, 0, 0, 512,
      y1, 1024, 0, 0, 0, cv_b1, nullptr, nullptr, nullptr, 0.f, 0.f);
  (void)hipMemsetAsync(Rg, 0, 8L * 1056 * 512 * 2, stream);
  glu_kernel<<<4096, 256, 0, stream>>>(y1, Rg);
  (void)hipMemsetAsync(stats, 0, 1024 * sizeof(float), stream);
  conv_gemm<<<dim3(16, 4, 8), 256, 0, stream>>>(Rg, wdKT, Rb, stats);
  bn_stats<<<2, 256, 0, stream>>>(stats, bn_g, bn_b);
  bn_silu<<<2048, 256, 0, stream>>>(Rb, stats, (short*)Rg);
  gemm_bt<128, 128, 2, 2, EPI_RES><<<dim3(64, 4, 1), 256, 0, stream>>>(
      (short*)Rg, 512, 0, 0, cw2b, 512, 0, 0, 512,
      xcur, 512, 0, 0, 0, cv_b2, nullptr, nullptr, xcur, 2.f, 1.f);

  // ---- FF2: x4 = 1.5 x3 + 0.5 (...) ----
  ln_rows<0, 0><<<2048, 256, 0, stream>>>(xcur, ff2_g, ff2_b, nullptr, Rb);
  gemm_bt<128, 128, 2, 2, EPI_SILU><<<dim3(64, 16, 1), 256, 0, stream>>>(
      Rb, 512, 0, 0, ff2w1T, 512, 0, 0, 512,
      hid, 2048, 0, 0, 0, ff2_b1, nullptr, nullptr, nullptr, 0.f, 0.f);
  gemm_bt<128, 128, 2, 2, EPI_RES><<<dim3(64, 4, 1), 256, 0, stream>>>(
      hid, 2048, 0, 0, ff2w2T, 2048, 0, 0, 2048,
      xcur, 512, 0, 0, 0, ff2_b2, nullptr, nullptr, xcur, 1.5f, 0.5f);

  // ---- final LN -> d_out (fp32) ----
  ln_rows<0, 1><<<2048, 256, 0, stream>>>(xcur, fin_g, fin_b, nullptr, (float*)d_out);
}

// plain elementwise fp32 -> bf16 cast (grid-stride)
__global__ __launch_bounds__(256) void cast_bf16(const float* __restrict__ in, short* __restrict__ out, long n)
{
  for (long i = (long)blockIdx.x * 256 + threadIdx.x; i < n; i += (long)gridDim.x * 256)
    out[i] = f2bfs(in[i]);
}

// Round 4
// 734.040 us; speedup vs baseline: 1.1265x; 1.1265x over previous
//
#include <hip/hip_runtime.h>

// ---------------------------------------------------------------------------
// Conformer block, MI355X gfx950. Inputs/outputs fp32; internal activations
// bf16 with fp32 accumulation via bf16 MFMA 16x16x32.
// Round 4: double-buffered LDS pipeline (T3 minimal 2-phase), conv as flat-K
// GEMM (lda=512 overlapping-window trick), bf16 attention intermediates with
// in-place softmax.
// ---------------------------------------------------------------------------

typedef __attribute__((ext_vector_type(4))) float f32x4;
typedef __attribute__((ext_vector_type(8))) short short8;
typedef __attribute__((ext_vector_type(4))) short s16x4;

__device__ __forceinline__ float bfs2f(short s) {
  unsigned u = ((unsigned)(unsigned short)s) << 16;
  float f; __builtin_memcpy(&f, &u, 4); return f;
}
__device__ __forceinline__ short f2bfs(float f) {
  unsigned u; __builtin_memcpy(&u, &f, 4);
  u = (u + 0x7FFFu + ((u >> 16) & 1u)) >> 16;   // RNE
  return (short)u;
}
__device__ __forceinline__ float sigmoidf_(float x) { return 1.f / (1.f + __expf(-x)); }

#define GLOADLDS(gsrc, ldst) \
  __builtin_amdgcn_global_load_lds((__attribute__((address_space(1))) void*)(gsrc), \
                                   (__attribute__((address_space(3))) void*)(ldst), 16, 0, 0)

enum { EPI_SILU = 0, EPI_F32BIAS = 1, EPI_RES = 2, EPI_QKV = 3, EPI_SBF16 = 4, EPI_SCRAM = 5 };

// ---------------------------------------------------------------------------
// Generic GEMM: C[M,N] = A[M,K] * BT[N,K]^T, bf16 in, fp32 accum.
// Double-buffered: stage(next) issued before ds_read+MFMA(cur), so the
// end-of-iteration vmcnt(0) drain overlaps with compute.
// ---------------------------------------------------------------------------
template<int BM, int BN, int WM, int WN, int EPI>
__global__ __launch_bounds__(256) void gemm_bt(
    const short* __restrict__ A, int lda, long zAh, long zAl,
    const short* __restrict__ BT, int ldbt, long zBh, long zBl,
    int K,
    void* C, int ldc, long zCh, long zCl, int zdiv,
    const float* bias, const float* bias2, const float* bias3,
    const float* resid, float alpha, float beta)
{
  constexpr int FM = BM / (WM * 16), FN = BN / (WN * 16);
  constexpr int AIT = (BM * 4) / 256, BIT = (BN * 4) / 256;
  __shared__ short sA[2][BM * 32];
  __shared__ short sB[2][BN * 32];
  const int tid = threadIdx.x;
  const int zhi = (int)(blockIdx.z >> zdiv);
  const int zlo = (int)(blockIdx.z & ((1u << zdiv) - 1u));
  A  += (long)zhi * zAh + (long)zlo * zAl;
  BT += (long)zhi * zBh + (long)zlo * zBl;
  char* cbase = (char*)C + (long)zhi * zCh + (long)zlo * zCl;
  const int m0 = blockIdx.x * BM, n0 = blockIdx.y * BN;

  auto stage = [&](int buf, int k0) {
#pragma unroll
    for (int it = 0; it < AIT; ++it) {
      int idx = it * 256 + tid;
      GLOADLDS(A + (long)(m0 + (idx >> 2)) * lda + k0 + (idx & 3) * 8, &sA[buf][idx * 8]);
    }
#pragma unroll
    for (int it = 0; it < BIT; ++it) {
      int idx = it * 256 + tid;
      GLOADLDS(BT + (long)(n0 + (idx >> 2)) * ldbt + k0 + (idx & 3) * 8, &sB[buf][idx * 8]);
    }
  };

  f32x4 acc[FM][FN];
#pragma unroll
  for (int i = 0; i < FM; ++i) {
#pragma unroll
    for (int j = 0; j < FN; ++j) acc[i][j] = (f32x4){0.f, 0.f, 0.f, 0.f};
  }
  const int lane = tid & 63, wid = tid >> 6;
  const int wm = wid / WN, wn = wid % WN;
  const int lr = lane & 15, kg = lane >> 4;
  const int aRow = wm * (BM / WM), bRow = wn * (BN / WN);

  stage(0, 0);
  asm volatile("s_waitcnt vmcnt(0)" ::: "memory");
  __syncthreads();

  for (int k0 = 0; k0 < K; k0 += 32) {
    const int cur = (k0 >> 5) & 1;
    if (k0 + 32 < K) stage(cur ^ 1, k0 + 32);
    short8 af[FM], bfr[FN];
#pragma unroll
    for (int mi = 0; mi < FM; ++mi)
      af[mi] = *(const short8*)&sA[cur][(aRow + mi * 16 + lr) * 32 + kg * 8];
#pragma unroll
    for (int ni = 0; ni < FN; ++ni)
      bfr[ni] = *(const short8*)&sB[cur][(bRow + ni * 16 + lr) * 32 + kg * 8];
#pragma unroll
    for (int mi = 0; mi < FM; ++mi) {
#pragma unroll
      for (int ni = 0; ni < FN; ++ni)
        acc[mi][ni] = __builtin_amdgcn_mfma_f32_16x16x32_bf16(af[mi], bfr[ni], acc[mi][ni], 0, 0, 0);
    }
    asm volatile("s_waitcnt vmcnt(0)" ::: "memory");
    __syncthreads();
  }

  // epilogue: C/D layout col = lane&15, row = (lane>>4)*4 + reg
  const int baseRow = m0 + aRow, baseCol = n0 + bRow;
#pragma unroll
  for (int mi = 0; mi < FM; ++mi) {
#pragma unroll
    for (int ni = 0; ni < FN; ++ni) {
      const int col = baseCol + ni * 16 + lr;
#pragma unroll
      for (int r = 0; r < 4; ++r) {
        const int row = baseRow + mi * 16 + kg * 4 + r;
        float v = acc[mi][ni][r];
        if (EPI == EPI_SILU) {
          v += bias[col];
          v = v * sigmoidf_(v);
          ((short*)cbase)[(long)row * ldc + col] = f2bfs(v);
        } else if (EPI == EPI_F32BIAS) {
          v += bias[col];
          ((float*)cbase)[(long)row * ldc + col] = v;
        } else if (EPI == EPI_RES) {
          v += bias[col];
          float rv = resid[(long)row * ldc + col];
          ((float*)cbase)[(long)row * ldc + col] = alpha * rv + beta * v;
        } else if (EPI == EPI_QKV) {
          if (col < 512)       v = (v + bias[col]) * 0.125f;   // fold 1/sqrt(64) into q
          else if (col < 1024) v += bias2[col - 512];
          else                 v += bias3[col - 1024];
          ((short*)cbase)[(long)row * ldc + col] = f2bfs(v);
        } else if (EPI == EPI_SBF16) {
          ((short*)cbase)[(long)row * ldc + col] = f2bfs(v);
        } else if (EPI == EPI_SCRAM) {
          // o[b,h,t2,e] -> out[b, n>>3, (n&7)*64+e], n = h*1024 + t2 (h = zlo)
          int n = zlo * 1024 + row;
          ((short*)cbase)[(long)(n >> 3) * 512 + (n & 7) * 64 + col] = f2bfs(v);
        }
      }
    }
  }
}

// ---------------------------------------------------------------------------
// Conv as flat-K GEMM: implicit A matrix IS glu_pad with lda=512 (overlapping
// windows): A[t][kk*512+i] = glu_pad[b][t0+t+kk+1][i]. BT = wdET[e][kk*512+i].
// K = 31*512 = 15872. BM=64, BN=128, dbuf pipeline, BN-stats epilogue.
// ---------------------------------------------------------------------------
__global__ __launch_bounds__(256) void conv_gemm(
    const short* __restrict__ glu_pad, const short* __restrict__ wdET,
    short* __restrict__ zout, float* stats)
{
  __shared__ short sA[2][64 * 32];
  __shared__ short sB[2][128 * 32];
  __shared__ float lsum[128], lsq[128];
  const int tid = threadIdx.x;
  const int b = blockIdx.z;
  const int t0 = blockIdx.x * 64, n0 = blockIdx.y * 128;
  const short* Abase = glu_pad + ((long)b * 1056 + t0 + 1) * 512;

  auto stage = [&](int buf, int k0) {
    {
      int idx = tid;  // 64 rows * 4 chunks
      GLOADLDS(Abase + (long)(idx >> 2) * 512 + k0 + (idx & 3) * 8, &sA[buf][idx * 8]);
    }
#pragma unroll
    for (int it = 0; it < 2; ++it) {
      int idx = it * 256 + tid;
      GLOADLDS(wdET + (long)(n0 + (idx >> 2)) * 15872 + k0 + (idx & 3) * 8, &sB[buf][idx * 8]);
    }
  };

  f32x4 acc[2][4];
#pragma unroll
  for (int i = 0; i < 2; ++i) {
#pragma unroll
    for (int j = 0; j < 4; ++j) acc[i][j] = (f32x4){0.f, 0.f, 0.f, 0.f};
  }
  const int lane = tid & 63, wid = tid >> 6;
  const int wm = wid >> 1, wn = wid & 1;
  const int lr = lane & 15, kg = lane >> 4;
  const int aRow = wm * 32, bRow = wn * 64;

  stage(0, 0);
  asm volatile("s_waitcnt vmcnt(0)" ::: "memory");
  __syncthreads();

  for (int k0 = 0; k0 < 15872; k0 += 32) {
    const int cur = (k0 >> 5) & 1;
    if (k0 + 32 < 15872) stage(cur ^ 1, k0 + 32);
    short8 af[2], bfr[4];
#pragma unroll
    for (int mi = 0; mi < 2; ++mi)
      af[mi] = *(const short8*)&sA[cur][(aRow + mi * 16 + lr) * 32 + kg * 8];
#pragma unroll
    for (int ni = 0; ni < 4; ++ni)
      bfr[ni] = *(const short8*)&sB[cur][(bRow + ni * 16 + lr) * 32 + kg * 8];
#pragma unroll
    for (int mi = 0; mi < 2; ++mi) {
#pragma unroll
      for (int ni = 0; ni < 4; ++ni)
        acc[mi][ni] = __builtin_amdgcn_mfma_f32_16x16x32_bf16(af[mi], bfr[ni], acc[mi][ni], 0, 0, 0);
    }
    asm volatile("s_waitcnt vmcnt(0)" ::: "memory");
    __syncthreads();
  }

  if (tid < 128) { lsum[tid] = 0.f; lsq[tid] = 0.f; }
  __syncthreads();
#pragma unroll
  for (int ni = 0; ni < 4; ++ni) {
    const int cloc = bRow + ni * 16 + lr;
    const int col = n0 + cloc;
    float s = 0.f, q = 0.f;
#pragma unroll
    for (int mi = 0; mi < 2; ++mi) {
#pragma unroll
      for (int r = 0; r < 4; ++r) {
        const int row = t0 + aRow + mi * 16 + kg * 4 + r;
        float v = acc[mi][ni][r];
        zout[((long)b * 1024 + row) * 512 + col] = f2bfs(v);
        s += v; q += v * v;
      }
    }
    atomicAdd(&lsum[cloc], s);
    atomicAdd(&lsq[cloc], q);
  }
  __syncthreads();
  if (tid < 128) {
    atomicAdd(&stats[n0 + tid], lsum[tid]);
    atomicAdd(&stats[512 + n0 + tid], lsq[tid]);
  }
}

// ---------------------------------------------------------------------------
// LayerNorm rows of 512 (fp32 in), one wave per row (4 rows/block).
// ---------------------------------------------------------------------------
template<int ADDPE, int OUTF32>
__global__ __launch_bounds__(256) void ln_rows(
    const float* __restrict__ X, const float* __restrict__ g, const float* __restrict__ b,
    const float* __restrict__ pe, void* __restrict__ Y)
{
  const int row = blockIdx.x * 4 + (threadIdx.x >> 6);
  const int lane = threadIdx.x & 63;
  const int c0 = lane * 8;
  const float* src = X + (long)row * 512 + c0;
  f32x4 a = *(const f32x4*)src, c = *(const f32x4*)(src + 4);
  float x[8] = {a[0], a[1], a[2], a[3], c[0], c[1], c[2], c[3]};
  float s = 0.f, q = 0.f;
#pragma unroll
  for (int j = 0; j < 8; ++j) { s += x[j]; q += x[j] * x[j]; }
#pragma unroll
  for (int off = 32; off > 0; off >>= 1) { s += __shfl_xor(s, off); q += __shfl_xor(q, off); }
  const float mean = s * (1.f / 512.f);
  const float var = q * (1.f / 512.f) - mean * mean;
  const float rstd = rsqrtf(var + 1e-5f);
  f32x4 g0 = *(const f32x4*)(g + c0), g1 = *(const f32x4*)(g + c0 + 4);
  f32x4 b0 = *(const f32x4*)(b + c0), b1 = *(const f32x4*)(b + c0 + 4);
  float gg[8] = {g0[0], g0[1], g0[2], g0[3], g1[0], g1[1], g1[2], g1[3]};
  float bb[8] = {b0[0], b0[1], b0[2], b0[3], b1[0], b1[1], b1[2], b1[3]};
  float y[8];
#pragma unroll
  for (int j = 0; j < 8; ++j) {
    y[j] = (x[j] - mean) * rstd * gg[j] + bb[j];
    if (ADDPE) y[j] += pe[(long)(row & 1023) * 512 + c0 + j];
  }
  if (OUTF32) {
    float* dst = (float*)Y + (long)row * 512 + c0;
    *(f32x4*)dst = (f32x4){y[0], y[1], y[2], y[3]};
    *(f32x4*)(dst + 4) = (f32x4){y[4], y[5], y[6], y[7]};
  } else {
    short8 o;
#pragma unroll
    for (int j = 0; j < 8; ++j) o[j] = f2bfs(y[j]);
    *(short8*)((short*)Y + (long)row * 512 + c0) = o;
  }
}

// ---------------------------------------------------------------------------
// In-place row softmax over 1024 bf16. One wave per row, 16 elems/lane.
// ---------------------------------------------------------------------------
__global__ __launch_bounds__(256) void softmax_rows_bf(short* __restrict__ S)
{
  const int gw = blockIdx.x * 4 + (threadIdx.x >> 6);
  const int lane = threadIdx.x & 63;
  short* p = S + (long)gw * 1024 + lane * 16;
  short8 r0 = *(const short8*)p;
  short8 r1 = *(const short8*)(p + 8);
  float v[16];
#pragma unroll
  for (int j = 0; j < 8; ++j) { v[j] = bfs2f(r0[j]); v[8 + j] = bfs2f(r1[j]); }
  float m = v[0];
#pragma unroll
  for (int j = 1; j < 16; ++j) m = fmaxf(m, v[j]);
#pragma unroll
  for (int off = 32; off > 0; off >>= 1) m = fmaxf(m, __shfl_xor(m, off));
  float s = 0.f;
#pragma unroll
  for (int j = 0; j < 16; ++j) { v[j] = __expf(v[j] - m); s += v[j]; }
#pragma unroll
  for (int off = 32; off > 0; off >>= 1) s += __shfl_xor(s, off);
  const float inv = 1.f / s;
  short8 o0, o1;
#pragma unroll
  for (int j = 0; j < 8; ++j) { o0[j] = f2bfs(v[j] * inv); o1[j] = f2bfs(v[8 + j] * inv); }
  *(short8*)p = o0;
  *(short8*)(p + 8) = o1;
}

// ---------------------------------------------------------------------------
// 64x64-tile transpose -> bf16 out. INF32: fp32 input (weights) or bf16 input.
// ---------------------------------------------------------------------------
template<int INF32>
__global__ __launch_bounds__(256) void transpose64(
    const void* __restrict__ in_, int ldin, short* __restrict__ out, int ldout,
    int ctiles, int zshift, long zh_in, long zl_in, long z_out)
{
  __shared__ short t[64][72];
  const int z = blockIdx.z;
  const long inoff = (long)(z >> zshift) * zh_in + (long)(z & ((1 << zshift) - 1)) * zl_in;
  const int tr = blockIdx.x / ctiles, tc = blockIdx.x % ctiles;
  short* dst = out + (long)z * z_out + (long)(tc * 64) * ldout + tr * 64;
  const int tid = threadIdx.x;
#pragma unroll
  for (int p = 0; p < 2; ++p) {
    int idx = p * 256 + tid;
    int r = idx >> 3, c8 = (idx & 7) * 8;
    if (INF32) {
      const float* src = (const float*)in_ + inoff + (long)(tr * 64 + r) * ldin + tc * 64 + c8;
      f32x4 v0 = *(const f32x4*)src, v1 = *(const f32x4*)(src + 4);
#pragma unroll
      for (int j = 0; j < 4; ++j) { t[r][c8 + j] = f2bfs(v0[j]); t[r][c8 + 4 + j] = f2bfs(v1[j]); }
    } else {
      const short* src = (const short*)in_ + inoff + (long)(tr * 64 + r) * ldin + tc * 64 + c8;
      short8 v = *(const short8*)src;
#pragma unroll
      for (int j = 0; j < 8; ++j) t[r][c8 + j] = v[j];
    }
  }
  __syncthreads();
#pragma unroll
  for (int p = 0; p < 2; ++p) {
    int idx = p * 256 + tid;
    int c = idx >> 3, r8 = (idx & 7) * 8;
    short8 v;
#pragma unroll
    for (int j = 0; j < 8; ++j) v[j] = t[r8 + j][c];
    *(short8*)(dst + (long)c * ldout + r8) = v;
  }
}

// wdET[e][kk*512 + i] = wd[e][i][kk], fp32 -> bf16
__global__ __launch_bounds__(256) void wd_pack(const float* __restrict__ wd, short* __restrict__ wdET)
{
  const int gid = blockIdx.x * 256 + threadIdx.x;  // 262144 = 512*512
  const int e = gid >> 9, i = gid & 511;
  const float* src = wd + ((long)e * 512 + i) * 31;
  short* dst = wdET + (long)e * 15872 + i;
#pragma unroll
  for (int kk = 0; kk < 31; ++kk)
    dst[kk * 512] = f2bfs(src[kk]);
}

// pe[t][2p] = sin(t * 10000^(-p/256)), pe[t][2p+1] = cos(...)
__global__ __launch_bounds__(256) void pe_init(float* __restrict__ pe)
{
  const int gid = blockIdx.x * 256 + threadIdx.x;  // 262144 = 1024*256
  const int t = gid >> 8, p = gid & 255;
  const float freq = __expf(-(float)p * (9.210340371976184f / 256.f));
  const float ang = (float)t * freq;
  pe[(long)t * 512 + 2 * p]     = sinf(ang);
  pe[(long)t * 512 + 2 * p + 1] = cosf(ang);
}

// glu = a * sigmoid(g) from y1[N][1024] fp32 -> glu_pad[b][16+t][512] bf16
__global__ __launch_bounds__(256) void glu_kernel(const float* __restrict__ y1, short* __restrict__ gp)
{
  const int gid = blockIdx.x * 256 + threadIdx.x;  // 1048576
  const int row = gid >> 7;
  const int ci = (gid & 127) * 4;
  const float* base = y1 + (long)row * 1024;
  f32x4 a = *(const f32x4*)(base + ci);
  f32x4 g = *(const f32x4*)(base + 512 + ci);
  const int b = row >> 10, t = row & 1023;
  s16x4 o;
#pragma unroll
  for (int j = 0; j < 4; ++j) o[j] = f2bfs(a[j] * sigmoidf_(g[j]));
  *(s16x4*)(gp + ((long)b * 1056 + 16 + t) * 512 + ci) = o;
}

__global__ void bn_stats(float* stats, const float* __restrict__ bn_g, const float* __restrict__ bn_b)
{
  const int c = blockIdx.x * 256 + threadIdx.x;
  if (c < 512) {
    float mean = stats[c] * (1.f / 8192.f);
    float var = stats[512 + c] * (1.f / 8192.f) - mean * mean;
    float sc = bn_g[c] * rsqrtf(var + 1e-5f);
    stats[1024 + c] = sc;
    stats[1536 + c] = bn_b[c] - mean * sc;
  }
}

__global__ __launch_bounds__(256) void bn_silu(const short* __restrict__ z, const float* __restrict__ stats,
                                               short* __restrict__ out)
{
  const long base = ((long)blockIdx.x * 256 + threadIdx.x) * 8;
  const int c0 = (int)(base & 511);
  short8 v = *(const short8*)(z + base);
  short8 o;
#pragma unroll
  for (int j = 0; j < 8; ++j) {
    const int c = c0 + j;
    float y = bfs2f(v[j]) * stats[1024 + c] + stats[1536 + c];
    o[j] = f2bfs(y * sigmoidf_(y));
  }
  *(short8*)(out + base) = o;
}

// plain elementwise fp32 -> bf16 cast (grid-stride)
__global__ __launch_bounds__(256) void cast_bf16(const float* __restrict__ in, short* __restrict__ out, long n)
{
  for (long i = (long)blockIdx.x * 256 + threadIdx.x; i < n; i += (long)gridDim.x * 256)
    out[i] = f2bfs(in[i]);
}

// ---------------------------------------------------------------------------
extern "C" void kernel_launch(void* const* d_in, const int* in_sizes, int n_in,
                              void* d_out, int out_size, void* d_ws, size_t ws_size,
                              hipStream_t stream)
{
  (void)in_sizes; (void)n_in; (void)out_size; (void)ws_size;
  const float* x_in   = (const float*)d_in[0];
  const float* ff1_g  = (const float*)d_in[1];
  const float* ff1_bb = (const float*)d_in[2];
  const float* ff1_w1 = (const float*)d_in[3];
  const float* ff1_b1 = (const float*)d_in[4];
  const float* ff1_w2 = (const float*)d_in[5];
  const float* ff1_b2 = (const float*)d_in[6];
  const float* mha_g  = (const float*)d_in[7];
  const float* mha_b  = (const float*)d_in[8];
  const float* wq     = (const float*)d_in[9];
  const float* bq     = (const float*)d_in[10];
  const float* wk     = (const float*)d_in[11];
  const float* bk     = (const float*)d_in[12];
  const float* wv     = (const float*)d_in[13];
  const float* bv     = (const float*)d_in[14];
  const float* wo     = (const float*)d_in[15];
  const float* bo     = (const float*)d_in[16];
  const float* cv_g   = (const float*)d_in[17];
  const float* cv_b   = (const float*)d_in[18];
  const float* cv_w1  = (const float*)d_in[19];
  const float* cv_b1  = (const float*)d_in[20];
  const float* cv_wd  = (const float*)d_in[21];
  const float* bn_g   = (const float*)d_in[22];
  const float* bn_b   = (const float*)d_in[23];
  const float* cv_w2  = (const float*)d_in[24];
  const float* cv_b2  = (const float*)d_in[25];
  const float* ff2_g  = (const float*)d_in[26];
  const float* ff2_b  = (const float*)d_in[27];
  const float* ff2_w1 = (const float*)d_in[28];
  const float* ff2_b1 = (const float*)d_in[29];
  const float* ff2_w2 = (const float*)d_in[30];
  const float* ff2_b2 = (const float*)d_in[31];
  const float* fin_g  = (const float*)d_in[32];
  const float* fin_b  = (const float*)d_in[33];

  size_t off = 0;
  char* wsb = (char*)d_ws;
  auto take = [&](size_t n) { char* p = wsb + off; off += (n + 255) & ~(size_t)255; return p; };
  short* ff1w1T = (short*)take(2048L * 512 * 2);
  short* ff1w2T = (short*)take(512L * 2048 * 2);
  short* qkvT   = (short*)take(1536L * 512 * 2);
  short* woT    = (short*)take(512L * 512 * 2);
  short* cw1b   = (short*)take(1024L * 512 * 2);   // cv_w1 bf16 (already [out,in])
  short* cw2b   = (short*)take(512L * 512 * 2);    // cv_w2 bf16
  short* wdET   = (short*)take(512L * 15872 * 2);  // wd repacked [e][kk*512+i]
  short* ff2w1T = (short*)take(2048L * 512 * 2);
  short* ff2w2T = (short*)take(512L * 2048 * 2);
  float* xcur   = (float*)take(8192L * 512 * 4);
  char*  Ra     = take(8192L * 2048 * 2);          // hid bf16 (32MB) / qkv bf16 / y1 fp32
  short* Rb     = (short*)take(8192L * 512 * 2);   // ln out / att_o / conv z
  short* Rg     = (short*)take(8L * 1056 * 512 * 2); // glu_pad / bn act
  short* Rs     = (short*)take(4L * 8 * 1024 * 1024 * 2); // scores chunk (4 batches, bf16)
  short* vt     = (short*)take(64L * 64 * 1024 * 2);   // V^T per (b,h)
  float* pe     = (float*)take(1024L * 512 * 4);
  float* stats  = (float*)take(2048L * 4);

  short* hid = (short*)Ra;
  short* qkv = (short*)Ra;
  float* y1  = (float*)Ra;

  // ---- weight packs (fp32 -> bf16; per call) ----
  transpose64<1><<<dim3(256, 1, 1), 256, 0, stream>>>(ff1_w1, 2048, ff1w1T, 512, 32, 0, 0, 0, 0);
  transpose64<1><<<dim3(256, 1, 1), 256, 0, stream>>>(ff1_w2, 512, ff1w2T, 2048, 8, 0, 0, 0, 0);
  transpose64<1><<<dim3(8, 1, 8), 256, 0, stream>>>(wq, 64, qkvT, 512, 1, 0, 32768, 0, 32768);
  transpose64<1><<<dim3(8, 1, 8), 256, 0, stream>>>(wk, 64, qkvT + 512 * 512, 512, 1, 0, 32768, 0, 32768);
  transpose64<1><<<dim3(8, 1, 8), 256, 0, stream>>>(wv, 64, qkvT + 1024 * 512, 512, 1, 0, 32768, 0, 32768);
  transpose64<1><<<dim3(64, 1, 1), 256, 0, stream>>>(wo, 512, woT, 512, 8, 0, 0, 0, 0);
  transpose64<1><<<dim3(256, 1, 1), 256, 0, stream>>>(ff2_w1, 2048, ff2w1T, 512, 32, 0, 0, 0, 0);
  transpose64<1><<<dim3(256, 1, 1), 256, 0, stream>>>(ff2_w2, 512, ff2w2T, 2048, 8, 0, 0, 0, 0);
  wd_pack<<<1024, 256, 0, stream>>>(cv_wd, wdET);
  pe_init<<<1024, 256, 0, stream>>>(pe);
  cast_bf16<<<2048, 256, 0, stream>>>(cv_w1, cw1b, 524288L);
  cast_bf16<<<1024, 256, 0, stream>>>(cv_w2, cw2b, 262144L);

  // ---- FF1: x1 = 1.5 x + 0.5 (silu(ln(x) W1 + b1) W2 + b2) ----
  ln_rows<0, 0><<<2048, 256, 0, stream>>>(x_in, ff1_g, ff1_bb, nullptr, Rb);
  gemm_bt<128, 128, 2, 2, EPI_SILU><<<dim3(64, 16, 1), 256, 0, stream>>>(
      Rb, 512, 0, 0, ff1w1T, 512, 0, 0, 512,
      hid, 2048, 0, 0, 0, ff1_b1, nullptr, nullptr, nullptr, 0.f, 0.f);
  gemm_bt<128, 128, 2, 2, EPI_RES><<<dim3(64, 4, 1), 256, 0, stream>>>(
      hid, 2048, 0, 0, ff1w2T, 2048, 0, 0, 2048,
      xcur, 512, 0, 0, 0, ff1_b2, nullptr, nullptr, x_in, 1.5f, 0.5f);

  // ---- MHSA: x2 = 2 x1 + (scramble(attn) Wo + bo) ----
  ln_rows<1, 0><<<2048, 256, 0, stream>>>(xcur, mha_g, mha_b, pe, Rb);
  gemm_bt<128, 128, 2, 2, EPI_QKV><<<dim3(64, 12, 1), 256, 0, stream>>>(
      Rb, 512, 0, 0, qkvT, 512, 0, 0, 512,
      qkv, 1536, 0, 0, 0, bq, bk, bv, nullptr, 0.f, 0.f);
  transpose64<0><<<dim3(16, 1, 64), 256, 0, stream>>>(qkv + 1024, 1536, vt, 1024, 1, 3,
                                                      1024L * 1536, 64, 65536);
  for (int b0 = 0; b0 < 8; b0 += 4) {
    const short* qb = qkv + (long)b0 * 1024 * 1536;
    gemm_bt<128, 128, 2, 2, EPI_SBF16><<<dim3(8, 8, 32), 256, 0, stream>>>(
        qb, 1536, 1024L * 1536, 64,
        qb + 512, 1536, 1024L * 1536, 64,
        64,
        Rs, 1024, 16777216L, 2097152L, 3,
        nullptr, nullptr, nullptr, nullptr, 0.f, 0.f);
    softmax_rows_bf<<<8192, 256, 0, stream>>>(Rs);
    gemm_bt<64, 64, 2, 2, EPI_SCRAM><<<dim3(16, 1, 32), 256, 0, stream>>>(
        Rs, 1024, 8L * 1048576, 1048576L,
        vt + (long)b0 * 8 * 65536, 1024, 8L * 65536, 65536L,
        1024,
        Rb + (long)b0 * 1024 * 512, 512, 1048576L, 0L, 3,
        nullptr, nullptr, nullptr, nullptr, 0.f, 0.f);
  }
  gemm_bt<128, 128, 2, 2, EPI_RES><<<dim3(64, 4, 1), 256, 0, stream>>>(
      Rb, 512, 0, 0, woT, 512, 0, 0, 512,
      xcur, 512, 0, 0, 0, bo, nullptr, nullptr, xcur, 2.f, 1.f);

  // ---- Conv module: x3 = 2 x2 + (W2 silu(BN(conv(glu(W1 ln(x2) + b1)))) + b2) ----
  ln_rows<0, 0><<<2048, 256, 0, stream>>>(xcur, cv_g, cv_b, nullptr, Rb);
  gemm_bt<128, 128, 2, 2, EPI_F32BIAS><<<dim3(64, 8, 1), 256, 0, stream>>>(
      Rb, 512, 0, 0, cw1b, 512, 0, 0, 512,
      y1, 1024, 0, 0, 0, cv_b1, nullptr, nullptr, nullptr, 0.f, 0.f);
  (void)hipMemsetAsync(Rg, 0, 8L * 1056 * 512 * 2, stream);
  glu_kernel<<<4096, 256, 0, stream>>>(y1, Rg);
  (void)hipMemsetAsync(stats, 0, 1024 * sizeof(float), stream);
  conv_gemm<<<dim3(16, 4, 8), 256, 0, stream>>>(Rg, wdET, Rb, stats);
  bn_stats<<<2, 256, 0, stream>>>(stats, bn_g, bn_b);
  bn_silu<<<2048, 256, 0, stream>>>(Rb, stats, (short*)Rg);
  gemm_bt<128, 128, 2, 2, EPI_RES><<<dim3(64, 4, 1), 256, 0, stream>>>(
      (short*)Rg, 512, 0, 0, cw2b, 512, 0, 0, 512,
      xcur, 512, 0, 0, 0, cv_b2, nullptr, nullptr, xcur, 2.f, 1.f);

  // ---- FF2: x4 = 1.5 x3 + 0.5 (...) ----
  ln_rows<0, 0><<<2048, 256, 0, stream>>>(xcur, ff2_g, ff2_b, nullptr, Rb);
  gemm_bt<128, 128, 2, 2, EPI_SILU><<<dim3(64, 16, 1), 256, 0, stream>>>(
      Rb, 512, 0, 0, ff2w1T, 512, 0, 0, 512,
      hid, 2048, 0, 0, 0, ff2_b1, nullptr, nullptr, nullptr, 0.f, 0.f);
  gemm_bt<128, 128, 2, 2, EPI_RES><<<dim3(64, 4, 1), 256, 0, stream>>>(
      hid, 2048, 0, 0, ff2w2T, 2048, 0, 0, 2048,
      xcur, 512, 0, 0, 0, ff2_b2, nullptr, nullptr, xcur, 1.5f, 0.5f);

  // ---- final LN -> d_out (fp32) ----
  ln_rows<0, 1><<<2048, 256, 0, stream>>>(xcur, fin_g, fin_b, nullptr, (float*)d_out);
}